// Round 16
// baseline (20.937 us; speedup 1.0000x reference)
//
#include <hip/hip_runtime.h>
#include <math.h>

// BipolarMorphological2D SMorph as a bf16 MFMA GEMM (R16).
// delta-form: e^kf = 1 + delta -> d = S_m + GEMM(m,delta); n = S_mlm + GEMM(..)
//   M = 7200 (s*2+sign), N = 256 (o*4+tbl), K = 576 (c*2+{m,mlm} per 3x3 pos)
// R16 vs R15: A3 global staging ELIMINATED. Each gemm block computes its
// 36.9KB A-tile (frag order) from x (L2-hot) into LDS (512-thr staging loop,
// 18 x-loads + 18 __logf each), MFMA loop reads A via lane-linear
// ds_read_b128; B from hot L2 (sole vmcnt user). Block = 8 waves
// (kq2 x nhf2 x msub2), 450 blocks -> 3600 waves (2x R15 TLP), 36 MFMA/wave.
// Prep shrinks to pixs+bt (150K threads). Combine/epilogue reuse staging LDS.

typedef float  f32x4 __attribute__((ext_vector_type(4)));
typedef short  s16x8 __attribute__((ext_vector_type(8)));

#define BB   4
#define CC   32
#define HH   32
#define WW   32
#define OO   64
#define HO   30
#define WO   30
#define NSP  900
#define KDIM 576

#define T1   131072            // branch1: pixel sums
#define TB   18432             // branch2: B pack

__device__ __forceinline__ unsigned short f2bf(float f) {
    unsigned u = __float_as_uint(f);
    return (unsigned short)((u + 0x7FFFu + ((u >> 16) & 1u)) >> 16);
}

// ---- prep: pixs[pix] = fp32 c-sums (Smp, Smlmp, Smn, Smlmn) per pixel
//            bt: bf16 B in MFMA-frag order: [ng(16)][step(18)][lane(64)] x 16B
__global__ __launch_bounds__(256) void smorph_prep(
    const float* __restrict__ x, const float* __restrict__ k1,
    const float* __restrict__ k2, float4* __restrict__ pixs,
    unsigned short* __restrict__ bt)
{
    const int t = blockIdx.x * 256 + threadIdx.x;

    if (t < T1) {
        const int pix = t >> 5, c = t & 31;
        const int b = pix >> 10, h = (pix >> 5) & 31, w = pix & 31;
        float v = x[b*32768 + c*1024 + h*32 + w];
        float mp = fmaxf(v, 0.1f), mn = fmaxf(-v, 0.1f);
        float lp = mp * logf(mp), ln_ = mn * logf(mn);
        float s0 = mp, s1 = lp, s2 = mn, s3 = ln_;
#pragma unroll
        for (int m = 16; m >= 1; m >>= 1) {
            s0 += __shfl_xor(s0, m); s1 += __shfl_xor(s1, m);
            s2 += __shfl_xor(s2, m); s3 += __shfl_xor(s3, m);
        }
        if (c == 0) pixs[pix] = make_float4(s0, s1, s2, s3);
    } else if (t < T1 + TB) {
        const int u3 = t - T1;
        const int o = u3 & 63, p = u3 >> 6;
        const float a = k1[u3], b2 = k2[u3];
        const float d1 = expm1f(a),  q1 = a  * expf(a);
        const float d2 = expm1f(b2), q2 = b2 * expf(b2);
        const float vals[4][2] = {{d1, 0.f}, {q1, d1}, {d2, 0.f}, {q2, d2}};
#pragma unroll
        for (int tbl = 0; tbl < 4; ++tbl) {
            const int n = o*4 + tbl;
#pragma unroll
            for (int ks = 0; ks < 2; ++ks) {
                const int k    = 2*p + ks;
                const int st   = k >> 5, k32 = k & 31;
                const int lane = (n & 15) + ((k32 >> 3) << 4);
                bt[((n >> 4)*18 + st)*512 + lane*8 + (k32 & 7)] = f2bf(vals[tbl][ks]);
            }
        }
    }
}

// ---- fused A-stage + GEMM + epilogue.
// 450 blocks (225 bm x 2 nh) x 512 thr (8 waves: kq2 x nhf2 x msub2).
// Wave: 16M (msub) x 64N (nh,nhf) x 9 steps (kq), 36 MFMA.
__global__ __launch_bounds__(512, 4) void smorph_gemm(
    const float* __restrict__ x, const unsigned short* __restrict__ bt,
    const float4* __restrict__ pixs, const float* __restrict__ bias,
    float* __restrict__ out)
{
    __shared__ __align__(16) uint4 ldsA[2304];   // 36,864 B A-tile (frag order)
    float* cmb = (float*)ldsA;                   // reuse: 16 KB K-combine
    float* epi = (float*)(ldsA + 1024);          // reuse: +16KB, 16.9 KB epilogue

    const int tid  = threadIdx.x;
    const int l    = tid & 63;
    const int w    = tid >> 6;                   // wave 0..7
    const int kq   = w >> 2;                     // K-half (step parity)
    const int nhf  = (w >> 1) & 1;               // N-quarter within half
    const int msub = w & 1;                      // M-half (16 rows)
    const int bm   = blockIdx.x >> 1;            // M-tile (16 s)
    const int nh   = blockIdx.x & 1;
    const int N0   = nh*128 + nhf*64;
    const int ng0  = N0 >> 4;
    const int lr   = l & 15;
    const int lg   = l >> 4;

    // ---- stage A tile: u = st*128 + mi*64 + lane (exact frag order)
    for (int u = tid; u < 2304; u += 512) {
        const int st  = u >> 7, r2 = u & 127;
        const int mi  = r2 >> 6, l2 = r2 & 63;
        const int lr2 = l2 & 15, lg2 = l2 >> 4;
        const int s    = bm*16 + mi*8 + (lr2 >> 1);
        const int sign = lr2 & 1;
        const int pos = st >> 1, khalf = st & 1;
        const int kh  = pos/3, kw = pos - 3*(pos/3);
        const int b   = s / NSP, r = s - b*NSP;
        const int ho  = r / WO,  wo = r - WO*(r/WO);
        const int base = b*32768 + (ho + kh)*32 + (wo + kw);
        const int c0   = khalf*16 + lg2*4;
        unsigned pk[4];
#pragma unroll
        for (int q = 0; q < 4; ++q) {
            float v = x[base + (c0 + q)*1024];
            float m = sign ? fmaxf(-v, 0.1f) : fmaxf(v, 0.1f);
            pk[q] = (unsigned)f2bf(m) | ((unsigned)f2bf(m * __logf(m)) << 16);
        }
        ldsA[u] = make_uint4(pk[0], pk[1], pk[2], pk[3]);
    }

    // ---- per-lane fp32 window sums (needed only by the store wave)
    float4 S;
    {
        const int s  = bm*16 + lr;
        const int b  = s / NSP, r = s - b*NSP;
        const int ho = r / WO,  wo = r - WO*(r/WO);
        const float4* P = pixs + (b*1024 + ho*32 + wo);
        float4 a = make_float4(0,0,0,0);
#pragma unroll
        for (int kh = 0; kh < 3; ++kh)
#pragma unroll
            for (int kw = 0; kw < 3; ++kw) {
                float4 v = P[kh*32 + kw];
                a.x += v.x; a.y += v.y; a.z += v.z; a.w += v.w;
            }
        S = a;
    }

    __syncthreads();   // A-tile staged

    const char*  pb = (const char*)bt;
    const uint4* Al = ldsA + msub*64 + l;

    f32x4 acc[4] = {};

#pragma unroll
    for (int s2 = 0; s2 < 9; ++s2) {
        const int step = s2*2 + kq;
        s16x8 a0 = *(const s16x8*)(Al + step*128);                       // LDS, lane-linear
        s16x8 b0 = *(const s16x8*)(pb + (((ng0+0)*18 + step)*64 + l)*16);// L2-hot
        s16x8 b1 = *(const s16x8*)(pb + (((ng0+1)*18 + step)*64 + l)*16);
        s16x8 b2 = *(const s16x8*)(pb + (((ng0+2)*18 + step)*64 + l)*16);
        s16x8 b3 = *(const s16x8*)(pb + (((ng0+3)*18 + step)*64 + l)*16);

        acc[0] = __builtin_amdgcn_mfma_f32_16x16x32_bf16(a0, b0, acc[0], 0, 0, 0);
        acc[1] = __builtin_amdgcn_mfma_f32_16x16x32_bf16(a0, b1, acc[1], 0, 0, 0);
        acc[2] = __builtin_amdgcn_mfma_f32_16x16x32_bf16(a0, b2, acc[2], 0, 0, 0);
        acc[3] = __builtin_amdgcn_mfma_f32_16x16x32_bf16(a0, b3, acc[3], 0, 0, 0);
    }

    __syncthreads();   // all A reads done; LDS reusable

    // ---- K-combine: kq1 -> cmb slot (nhf,msub), kq0 adds
    if (kq == 1) {
        float* dst = cmb + (nhf*2 + msub)*1024 + l;
#pragma unroll
        for (int ni = 0; ni < 4; ++ni)
#pragma unroll
            for (int r = 0; r < 4; ++r)
                dst[(ni*4 + r)*64] = acc[ni][r];
    }
    __syncthreads();
    if (kq == 0) {
        const float* srcp = cmb + (nhf*2 + msub)*1024 + l;
#pragma unroll
        for (int ni = 0; ni < 4; ++ni)
#pragma unroll
            for (int r = 0; r < 4; ++r)
                acc[ni][r] += srcp[(ni*4 + r)*64];

        // epilogue write: rows msub*16 + lg*4 + r, cols ni*16 + lr (pitch 66)
        float* E = epi + nhf*2112;
        const int wrbase = (msub*16 + lg*4)*66 + lr;
#pragma unroll
        for (int ni = 0; ni < 4; ++ni)
#pragma unroll
            for (int r = 0; r < 4; ++r)
                E[wrbase + r*66 + ni*16] = acc[ni][r];
    }
    __syncthreads();

    // ---- final transform + store: one wave per nhf (kq0, msub0)
    if (kq == 0 && msub == 0) {
        const float* E = epi + nhf*2112;
        const int sl = lr;
        const int s  = bm*16 + sl;
        const int b  = s / NSP;
        const int r900 = s - b*NSP;
#pragma unroll
        for (int oi = 0; oi < 4; ++oi) {
            int ol = lg*4 + oi;
            int o  = (N0 >> 2) + ol;
            float4 v0 = *(const float4*)&E[(2*sl + 0)*66 + ol*4];  // pos: d1,n1,d2,n2
            float4 v1 = *(const float4*)&E[(2*sl + 1)*66 + ol*4];  // neg
            float d1p = S.x + v0.x, n1p = S.y + v0.y;
            float d2p = S.x + v0.z, n2p = S.y + v0.w;
            float d1n = S.z + v1.x, n1n = S.w + v1.y;
            float d2n = S.z + v1.z, n2n = S.w + v1.w;
            float P = __expf(n1p/d1p) - __expf(n2p/d2p)
                    - __expf(n1n/d1n) + __expf(n2n/d2n);
            out[((size_t)(b*OO + o))*NSP + r900] = P + bias[o];
        }
    }
}

extern "C" void kernel_launch(void* const* d_in, const int* in_sizes, int n_in,
                              void* d_out, int out_size, void* d_ws, size_t ws_size,
                              hipStream_t stream) {
    const float* x    = (const float*)d_in[0];
    const float* k1   = (const float*)d_in[1];
    const float* k2   = (const float*)d_in[2];
    const float* bias = (const float*)d_in[3];

    char* ws = (char*)d_ws;
    float4*         pixs = (float4*)(ws);                 // 64 KB
    unsigned short* bt   = (unsigned short*)(ws + 0x10000); // 294,912 B
    float*          out  = (float*)d_out;

    hipLaunchKernelGGL(smorph_prep, dim3((T1 + TB + 255)/256), dim3(256), 0, stream,
                       x, k1, k2, pixs, bt);
    hipLaunchKernelGGL(smorph_gemm, dim3(450), dim3(512), 0, stream,
                       x, bt, pixs, bias, out);
}

// Round 17
// 19.753 us; speedup vs baseline: 1.0600x; 1.0600x over previous
//
#include <hip/hip_runtime.h>
#include <math.h>

// BipolarMorphological2D SMorph as a bf16 MFMA GEMM (R17).
// delta-form: e^kf = 1 + delta -> d = S_m + GEMM(m,delta); n = S_mlm + GEMM(..)
//   M = 7200 (s*2+sign), N = 256 (o*4+tbl), K = 576 (c*2+{m,mlm} per 3x3 pos)
// R17 vs R15/R16: kill the 9x-duplicated A-pack work. prep writes the UNIQUE
// bf16 table pixm[pix][sign][c] (1 MB, 262K logf = 8x less than im2col pack);
// gemm loads A-frags directly from pixm with offA+immA addressing (16
// lines/instr ~ coalescing floor, L2-hot). B stays frag-packed lane-linear.
// gemm keeps R15's winning shape: 450 blocks x 4 waves (kq2 x nhf2),
// K-split-2, LDS combine + epilogue transpose.

typedef float  f32x4 __attribute__((ext_vector_type(4)));
typedef short  s16x8 __attribute__((ext_vector_type(8)));

#define BB   4
#define CC   32
#define HH   32
#define WW   32
#define OO   64
#define HO   30
#define WO   30
#define NSP  900
#define KDIM 576

#define T1   131072            // branch1: pixel sums + pixm pack
#define TB   18432             // branch2: B pack

__device__ __forceinline__ unsigned short f2bf(float f) {
    unsigned u = __float_as_uint(f);
    return (unsigned short)((u + 0x7FFFu + ((u >> 16) & 1u)) >> 16);
}

// ---- prep: pixs[pix] = fp32 c-sums (Smp, Smlmp, Smn, Smlmn)
//            pixm[pix*64 + sign*32 + c] = packed bf16 (m | mlm<<16)
//            bt: bf16 B in MFMA-frag order: [ng(16)][step(18)][lane(64)] x 16B
__global__ __launch_bounds__(256) void smorph_prep(
    const float* __restrict__ x, const float* __restrict__ k1,
    const float* __restrict__ k2, float4* __restrict__ pixs,
    unsigned* __restrict__ pixm, unsigned short* __restrict__ bt)
{
    const int t = blockIdx.x * 256 + threadIdx.x;

    if (t < T1) {
        const int pix = t >> 5, c = t & 31;
        const int b = pix >> 10, h = (pix >> 5) & 31, w = pix & 31;
        float v = x[b*32768 + c*1024 + h*32 + w];
        float mp = fmaxf(v, 0.1f), mn = fmaxf(-v, 0.1f);
        float lp = mp * logf(mp), ln_ = mn * logf(mn);
        pixm[pix*64      + c] = (unsigned)f2bf(mp) | ((unsigned)f2bf(lp)  << 16);
        pixm[pix*64 + 32 + c] = (unsigned)f2bf(mn) | ((unsigned)f2bf(ln_) << 16);
        float s0 = mp, s1 = lp, s2 = mn, s3 = ln_;
#pragma unroll
        for (int m = 16; m >= 1; m >>= 1) {
            s0 += __shfl_xor(s0, m); s1 += __shfl_xor(s1, m);
            s2 += __shfl_xor(s2, m); s3 += __shfl_xor(s3, m);
        }
        if (c == 0) pixs[pix] = make_float4(s0, s1, s2, s3);
    } else if (t < T1 + TB) {
        const int u3 = t - T1;
        const int o = u3 & 63, p = u3 >> 6;
        const float a = k1[u3], b2 = k2[u3];
        const float d1 = expm1f(a),  q1 = a  * expf(a);
        const float d2 = expm1f(b2), q2 = b2 * expf(b2);
        const float vals[4][2] = {{d1, 0.f}, {q1, d1}, {d2, 0.f}, {q2, d2}};
#pragma unroll
        for (int tbl = 0; tbl < 4; ++tbl) {
            const int n = o*4 + tbl;
#pragma unroll
            for (int ks = 0; ks < 2; ++ks) {
                const int k    = 2*p + ks;
                const int st   = k >> 5, k32 = k & 31;
                const int lane = (n & 15) + ((k32 >> 3) << 4);
                bt[((n >> 4)*18 + st)*512 + lane*8 + (k32 & 7)] = f2bf(vals[tbl][ks]);
            }
        }
    }
}

// ---- GEMM: 450 blocks x 256 thr (4 waves: kq x nhf). Wave: 32M x 64N x 9 steps.
__global__ __launch_bounds__(256, 2) void smorph_gemm(
    const unsigned* __restrict__ pixm, const unsigned short* __restrict__ bt,
    const float4* __restrict__ pixs, const float* __restrict__ bias,
    float* __restrict__ out)
{
    __shared__ float cmb[2][2048];               // 16 KB: K-combine, r-major
    __shared__ __align__(16) float epi[2][32*66];// 16.9 KB: epilogue transpose

    const int tid = threadIdx.x;
    const int l   = tid & 63;
    const int w   = tid >> 6;                  // wave 0..3
    const int kq  = w >> 1;                    // K-half (step parity)
    const int nhf = w & 1;                     // N-half within block
    const int bm  = blockIdx.x >> 1;           // M-tile (16 s, 32 rows)
    const int nh  = blockIdx.x & 1;
    const int N0  = nh*128 + nhf*64;
    const int ng0 = N0 >> 4;

    const int lr = l & 15;
    const int lg = l >> 4;

    // ---- per-lane fp32 window sums (epilogue only)
    float4 S;
    {
        const int s  = bm*16 + lr;
        const int b  = s / NSP, r = s - b*NSP;
        const int ho = r / WO,  wo = r - WO*(r/WO);
        const float4* P = pixs + (b*1024 + ho*32 + wo);
        float4 a = make_float4(0,0,0,0);
#pragma unroll
        for (int kh = 0; kh < 3; ++kh)
#pragma unroll
            for (int kw = 0; kw < 3; ++kw) {
                float4 v = P[kh*32 + kw];
                a.x += v.x; a.y += v.y; a.z += v.z; a.w += v.w;
            }
        S = a;
    }

    // A lane byte-offsets into pixm: pix*256 + sign*128 + lg*16
    unsigned offA[2];
    {
        const int sign = lr & 1;
#pragma unroll
        for (int mi = 0; mi < 2; ++mi) {
            const int s  = bm*16 + mi*8 + (lr >> 1);
            const int b  = s / NSP, r = s - b*NSP;
            const int ho = r / WO,  wo = r - WO*(r/WO);
            const int pix = b*1024 + ho*32 + wo;
            offA[mi] = (unsigned)(pix*256 + sign*128 + lg*16);
        }
    }

    const char* pa = (const char*)pixm;
    const char* pb = (const char*)bt;

    f32x4 acc[2][4] = {};

#pragma unroll
    for (int s2 = 0; s2 < 9; ++s2) {
        const int step  = s2*2 + kq;           // this wave's 9 steps
        const int khkw  = step >> 1;
        const int kh    = khkw / 3, kw = khkw - 3*(khkw/3);
        const int khalf = step & 1;
        const unsigned immA = (unsigned)(kh*8192 + kw*256 + khalf*64);

        s16x8 a0 = *(const s16x8*)(pa + (offA[0] + immA));   // L2-hot, 16 lines
        s16x8 a1 = *(const s16x8*)(pa + (offA[1] + immA));
        s16x8 b0 = *(const s16x8*)(pb + (((ng0+0)*18 + step)*64 + l)*16);  // lane-linear
        s16x8 b1 = *(const s16x8*)(pb + (((ng0+1)*18 + step)*64 + l)*16);
        s16x8 b2 = *(const s16x8*)(pb + (((ng0+2)*18 + step)*64 + l)*16);
        s16x8 b3 = *(const s16x8*)(pb + (((ng0+3)*18 + step)*64 + l)*16);

        acc[0][0] = __builtin_amdgcn_mfma_f32_16x16x32_bf16(a0, b0, acc[0][0], 0, 0, 0);
        acc[0][1] = __builtin_amdgcn_mfma_f32_16x16x32_bf16(a0, b1, acc[0][1], 0, 0, 0);
        acc[0][2] = __builtin_amdgcn_mfma_f32_16x16x32_bf16(a0, b2, acc[0][2], 0, 0, 0);
        acc[0][3] = __builtin_amdgcn_mfma_f32_16x16x32_bf16(a0, b3, acc[0][3], 0, 0, 0);
        acc[1][0] = __builtin_amdgcn_mfma_f32_16x16x32_bf16(a1, b0, acc[1][0], 0, 0, 0);
        acc[1][1] = __builtin_amdgcn_mfma_f32_16x16x32_bf16(a1, b1, acc[1][1], 0, 0, 0);
        acc[1][2] = __builtin_amdgcn_mfma_f32_16x16x32_bf16(a1, b2, acc[1][2], 0, 0, 0);
        acc[1][3] = __builtin_amdgcn_mfma_f32_16x16x32_bf16(a1, b3, acc[1][3], 0, 0, 0);
    }

    // ---- K-combine: kq1 -> LDS (r-major, conflict-free), kq0 adds
    if (kq == 1) {
#pragma unroll
        for (int mi = 0; mi < 2; ++mi)
#pragma unroll
            for (int ni = 0; ni < 4; ++ni)
#pragma unroll
                for (int r = 0; r < 4; ++r)
                    cmb[nhf][(mi*16 + ni*4 + r)*64 + l] = acc[mi][ni][r];
    }
    __syncthreads();
    if (kq == 0) {
#pragma unroll
        for (int mi = 0; mi < 2; ++mi)
#pragma unroll
            for (int ni = 0; ni < 4; ++ni)
#pragma unroll
                for (int r = 0; r < 4; ++r)
                    acc[mi][ni][r] += cmb[nhf][(mi*16 + ni*4 + r)*64 + l];

        // epilogue write: acc -> epi[nhf] [row 0..31][col 0..63], pitch 66
        const int wrbase = lg*4*66 + lr;
#pragma unroll
        for (int mi = 0; mi < 2; ++mi)
#pragma unroll
            for (int ni = 0; ni < 4; ++ni)
#pragma unroll
                for (int r = 0; r < 4; ++r)
                    epi[nhf][wrbase + (mi*16 + r)*66 + ni*16] = acc[mi][ni][r];
    }
    __syncthreads();

    if (kq == 0) {
        const int sl = lr;
        const int s  = bm*16 + sl;
        const int b  = s / NSP;
        const int r900 = s - b*NSP;
#pragma unroll
        for (int oi = 0; oi < 4; ++oi) {
            int ol = lg*4 + oi;
            int o  = (N0 >> 2) + ol;
            float4 v0 = *(const float4*)&epi[nhf][(2*sl + 0)*66 + ol*4];  // pos
            float4 v1 = *(const float4*)&epi[nhf][(2*sl + 1)*66 + ol*4];  // neg
            float d1p = S.x + v0.x, n1p = S.y + v0.y;
            float d2p = S.x + v0.z, n2p = S.y + v0.w;
            float d1n = S.z + v1.x, n1n = S.w + v1.y;
            float d2n = S.z + v1.z, n2n = S.w + v1.w;
            float P = __expf(n1p/d1p) - __expf(n2p/d2p)
                    - __expf(n1n/d1n) + __expf(n2n/d2n);
            out[((size_t)(b*OO + o))*NSP + r900] = P + bias[o];
        }
    }
}

extern "C" void kernel_launch(void* const* d_in, const int* in_sizes, int n_in,
                              void* d_out, int out_size, void* d_ws, size_t ws_size,
                              hipStream_t stream) {
    const float* x    = (const float*)d_in[0];
    const float* k1   = (const float*)d_in[1];
    const float* k2   = (const float*)d_in[2];
    const float* bias = (const float*)d_in[3];

    char* ws = (char*)d_ws;
    float4*         pixs = (float4*)(ws);                    // 64 KB
    unsigned*       pixm = (unsigned*)(ws + 0x10000);        // 1 MB
    unsigned short* bt   = (unsigned short*)(ws + 0x110000); // 294,912 B
    float*          out  = (float*)d_out;

    hipLaunchKernelGGL(smorph_prep, dim3((T1 + TB + 255)/256), dim3(256), 0, stream,
                       x, k1, k2, pixs, pixm, bt);
    hipLaunchKernelGGL(smorph_gemm, dim3(450), dim3(256), 0, stream,
                       pixm, bt, pixs, bias, out);
}